// Round 1
// baseline (255.726 us; speedup 1.0000x reference)
//
#include <hip/hip_runtime.h>
#include <stdint.h>

typedef unsigned short u16;
typedef __bf16 bf16x8 __attribute__((ext_vector_type(8)));
typedef float f32x4 __attribute__((ext_vector_type(4)));

#define DEVINL __device__ __forceinline__

DEVINL u16 f2bf(float f){
  uint32_t x = __float_as_uint(f);
  uint32_t r = (x + 0x7fffu + ((x >> 16) & 1u)) >> 16;
  return (u16)r;
}

DEVINL float wave_sum(float v){
#pragma unroll
  for (int off = 32; off; off >>= 1) v += __shfl_xor(v, off);
  return v;
}

DEVINL void gload_lds16(const void* g, void* l){
  __builtin_amdgcn_global_load_lds(
      (const __attribute__((address_space(1))) uint32_t*)g,
      (__attribute__((address_space(3))) uint32_t*)l, 16, 0, 0);
}

// ---------------- cf = relu(Wp @ pf + bp), one wave per output row -----------
__global__ __launch_bounds__(256) void cf_kernel(
    const float* __restrict__ Wp, const float* __restrict__ pf,
    const float* __restrict__ bp, float* __restrict__ feats, int* __restrict__ flag)
{
  if (blockIdx.x == 0 && threadIdx.x == 0) *flag = 0;
  const int lane = threadIdx.x & 63, wid = threadIdx.x >> 6;
  const int n = (blockIdx.x << 2) + wid;            // 0..65535
  const float4* row = (const float4*)(Wp + (size_t)n * 512);
  const float4* p   = (const float4*)pf;
  float4 w0 = row[lane*2], w1 = row[lane*2+1];
  float4 p0 = p[lane*2],  p1 = p[lane*2+1];
  float v = w0.x*p0.x + w0.y*p0.y + w0.z*p0.z + w0.w*p0.w
          + w1.x*p1.x + w1.y*p1.y + w1.z*p1.z + w1.w*p1.w;
  v = wave_sum(v);
  if (lane == 0){
    float r = fmaxf(v + bp[n], 0.f);
    feats[(size_t)(n >> 9) * 1536 + (n & 511)] = r;   // cf -> feats cols [0,512)
  }
}

// ---------------- generic small GEMM: C[m,n] = act(A[m,:]·W[n,:] + b[n]) -----
// grid (ceil(N/4), 16); 4 waves/block, 8 m-rows per wave, M=128.
template<bool RELU>
__global__ __launch_bounds__(256) void gemm_dot(
    const float* __restrict__ A, int lda,
    const float* __restrict__ W, int ldw,
    const float* __restrict__ bias,
    float* __restrict__ C, int ldc, float* __restrict__ C2,
    int N, int K)
{
  const int lane = threadIdx.x & 63, wid = threadIdx.x >> 6;
  const int n = blockIdx.x * 4 + wid;
  const int m0 = blockIdx.y * 8;
  if (n >= N) return;
  const float* wrow = W + (size_t)n * ldw + lane * 4;
  const float* arow = A + (size_t)m0 * lda + lane * 4;
  float acc[8] = {0,0,0,0,0,0,0,0};
  for (int kc = 0; kc < K; kc += 256){
    float4 w4 = *(const float4*)(wrow + kc);
#pragma unroll
    for (int r = 0; r < 8; r++){
      float4 a4 = *(const float4*)(arow + (size_t)r * lda + kc);
      acc[r] = fmaf(w4.x, a4.x, fmaf(w4.y, a4.y, fmaf(w4.z, a4.z, fmaf(w4.w, a4.w, acc[r]))));
    }
  }
#pragma unroll
  for (int r = 0; r < 8; r++){
    float v = wave_sum(acc[r]);
    if (lane == 0){
      float o = v + (bias ? bias[n] : 0.f);
      if (RELU) o = fmaxf(o, 0.f);
      C[(size_t)(m0 + r) * ldc + n] = o;
      if (C2) C2[(size_t)(m0 + r) * ldc + n] = o;
    }
  }
}

// ---------------- el (bf16) + eel (f32) + has_edges; one wave per (i,j) ------
__global__ __launch_bounds__(256) void el_kernel(
    const float* __restrict__ P, const float* __restrict__ Q,
    const float* __restrict__ Wee, const float* __restrict__ bee,
    const float* __restrict__ ex,
    u16* __restrict__ elb, float* __restrict__ eelOut, int* __restrict__ flag)
{
  const int lane = threadIdx.x & 63, wid = threadIdx.x >> 6;
  const int row = (blockIdx.x << 2) + wid;          // 0..16383
  const int i = row >> 7, j = row & 127;
  const int k0 = lane << 3;
  float4 p0 = *(const float4*)(P + (size_t)i*512 + k0);
  float4 p1 = *(const float4*)(P + (size_t)i*512 + k0 + 4);
  float4 q0 = *(const float4*)(Q + (size_t)j*512 + k0);
  float4 q1 = *(const float4*)(Q + (size_t)j*512 + k0 + 4);
  float e[8];
  e[0]=fmaxf(p0.x+q0.x,0.f); e[1]=fmaxf(p0.y+q0.y,0.f);
  e[2]=fmaxf(p0.z+q0.z,0.f); e[3]=fmaxf(p0.w+q0.w,0.f);
  e[4]=fmaxf(p1.x+q1.x,0.f); e[5]=fmaxf(p1.y+q1.y,0.f);
  e[6]=fmaxf(p1.z+q1.z,0.f); e[7]=fmaxf(p1.w+q1.w,0.f);
  union { u16 u[8]; uint4 q4; } o;
#pragma unroll
  for (int c = 0; c < 8; c++) o.u[c] = f2bf(e[c]);
  *(uint4*)(elb + (size_t)row*512 + k0) = o.q4;
  float acc[4];
#pragma unroll
  for (int t = 0; t < 4; t++){
    float4 w0 = *(const float4*)(Wee + t*512 + k0);
    float4 w1 = *(const float4*)(Wee + t*512 + k0 + 4);
    float a = e[0]*w0.x + e[1]*w0.y + e[2]*w0.z + e[3]*w0.w
            + e[4]*w1.x + e[5]*w1.y + e[6]*w1.z + e[7]*w1.w;
    acc[t] = wave_sum(a);
  }
  if (lane == 0){
    float4 r = make_float4(acc[0]+bee[0], acc[1]+bee[1], acc[2]+bee[2], acc[3]+bee[3]);
    *(float4*)(eelOut + (size_t)row*4) = r;
    if ((ex[i] > 0.f) && (ex[j] > 0.f) &&
        (r.x > 0.f || r.y > 0.f || r.z > 0.f || r.w > 0.f))
      atomicOr(flag, 1);
  }
}

// ---------------- Wf3 (Wop cols 1024:1536) -> bf16 --------------------------
__global__ __launch_bounds__(256) void wconv_kernel(
    const float* __restrict__ Wop, u16* __restrict__ wfb)
{
  const int t = blockIdx.x * 256 + threadIdx.x;     // 0..65535
  const int e = t * 8;                              // elem in [2][512][512]
  const int it = e >> 18;
  const int rem = e & 262143;
  const int h = rem >> 9, k = rem & 511;
  const float* src = Wop + (size_t)it*788480 + (size_t)h*1540 + 1024 + k;
  float4 v0 = ((const float4*)src)[0];
  float4 v1 = ((const float4*)src)[1];
  union { u16 u[8]; uint4 q4; } o;
  o.u[0]=f2bf(v0.x); o.u[1]=f2bf(v0.y); o.u[2]=f2bf(v0.z); o.u[3]=f2bf(v0.w);
  o.u[4]=f2bf(v1.x); o.u[5]=f2bf(v1.y); o.u[6]=f2bf(v1.z); o.u[7]=f2bf(v1.w);
  *(uint4*)(wfb + e) = o.q4;
}

// ---------------- fused E-GEMM + msg + masked max per iteration -------------
// grid (4 h-tiles, 128 i); block = 4 waves; tile: 128 j x 128 h, K=512.
__global__ __launch_bounds__(256) void iter_kernel(
    const u16* __restrict__ el, const u16* __restrict__ wfb,
    const float* __restrict__ Aterm, const float* __restrict__ Bterm,
    const float* __restrict__ eel, const float* __restrict__ ex,
    const float* __restrict__ wopWt,      // Wop + it*788480 (for Wt cols 1536..)
    const int* __restrict__ flag,
    float* __restrict__ feats, int it)
{
  __shared__ u16 lds[2][2][4096];   // [buf][A/B][128 rows x 32 cols bf16]
  __shared__ float smax[2][128];
  const int tid = threadIdx.x;
  const int lane = tid & 63, wid = tid >> 6;
  const int wr = wid >> 1, wc = wid & 1;
  const int i = blockIdx.y;
  const int hc0 = blockIdx.x << 7;

  // staging: chunk c in [0,512), 16B each; round0 c=tid, round1 c=256+tid.
  // LDS is linear; source col-slot is XOR-swizzled so swizzled ds_reads match.
  const int rA0 = tid >> 2, s0 = tid & 3;
  const int rA1 = 64 + (tid >> 2);
  const int cA0 = (s0 ^ ((rA0 >> 1) & 3)) << 3;
  const int cA1 = (s0 ^ ((rA1 >> 1) & 3)) << 3;
  const u16* sA0 = el  + (size_t)(i*128 + rA0)*512 + cA0;
  const u16* sA1 = el  + (size_t)(i*128 + rA1)*512 + cA1;
  const u16* sB0 = wfb + (size_t)(hc0 + rA0)*512 + cA0;
  const u16* sB1 = wfb + (size_t)(hc0 + rA1)*512 + cA1;

  const int slog = lane >> 4;
  int byteA[4], byteB[4];
#pragma unroll
  for (int f = 0; f < 4; f++){
    int ra = wr*64 + f*16 + (lane & 15);
    byteA[f] = ra*64 + ((slog ^ ((ra >> 1) & 3)) << 4);
    int rb = wc*64 + f*16 + (lane & 15);
    byteB[f] = rb*64 + ((slog ^ ((rb >> 1) & 3)) << 4);
  }

  f32x4 acc[4][4] = {};

  auto stage = [&](int buf, int ks){
    const int k0 = ks << 5;
    u16* dA = &lds[buf][0][0];
    u16* dB = &lds[buf][1][0];
    gload_lds16(sA0 + k0, dA + tid*8);
    gload_lds16(sA1 + k0, dA + 2048 + tid*8);
    gload_lds16(sB0 + k0, dB + tid*8);
    gload_lds16(sB1 + k0, dB + 2048 + tid*8);
  };

  stage(0, 0);
  __syncthreads();
  for (int ks = 0; ks < 16; ks++){
    const int cur = ks & 1;
    if (ks < 15) stage(cur ^ 1, ks + 1);
    const char* baseA = (const char*)&lds[cur][0][0];
    const char* baseB = (const char*)&lds[cur][1][0];
    bf16x8 a[4], b[4];
#pragma unroll
    for (int f = 0; f < 4; f++){
      a[f] = *(const bf16x8*)(baseA + byteA[f]);
      b[f] = *(const bf16x8*)(baseB + byteB[f]);
    }
#pragma unroll
    for (int fa = 0; fa < 4; fa++)
#pragma unroll
      for (int fb = 0; fb < 4; fb++)
        acc[fa][fb] = __builtin_amdgcn_mfma_f32_16x16x32_bf16(a[fa], b[fb], acc[fa][fb], 0, 0, 0);
    __syncthreads();
  }

  // epilogue: msg = relu(pre + e0*Wt), masked max over (j,t)
  const bool mi = ex[i] > 0.f;
  float Ah[4]; float4 wt[4]; int hg[4];
#pragma unroll
  for (int fb = 0; fb < 4; fb++){
    hg[fb] = hc0 + wc*64 + fb*16 + (lane & 15);
    Ah[fb] = Aterm[i*512 + hg[fb]];
    wt[fb] = *(const float4*)(wopWt + (size_t)hg[fb]*1540 + 1536);
  }
  float tm[4] = {0.f, 0.f, 0.f, 0.f};
#pragma unroll
  for (int fa = 0; fa < 4; fa++){
    const int j0 = wr*64 + fa*16 + slog*4;
#pragma unroll
    for (int r = 0; r < 4; r++){
      const int j = j0 + r;
      float4 e4 = *(const float4*)(eel + (size_t)(i*128 + j)*4);
      const bool mj = mi && (ex[j] > 0.f);
      const bool c0 = mj && (e4.x > 0.f), c1 = mj && (e4.y > 0.f);
      const bool c2 = mj && (e4.z > 0.f), c3 = mj && (e4.w > 0.f);
#pragma unroll
      for (int fb = 0; fb < 4; fb++){
        float val = acc[fa][fb][r] + Ah[fb] + Bterm[(size_t)j*512 + hg[fb]];
        if (c0) tm[fb] = fmaxf(tm[fb], val + e4.x*wt[fb].x);
        if (c1) tm[fb] = fmaxf(tm[fb], val + e4.y*wt[fb].y);
        if (c2) tm[fb] = fmaxf(tm[fb], val + e4.z*wt[fb].z);
        if (c3) tm[fb] = fmaxf(tm[fb], val + e4.w*wt[fb].w);
      }
    }
  }
#pragma unroll
  for (int fb = 0; fb < 4; fb++){
    float v = tm[fb];
    v = fmaxf(v, __shfl_xor(v, 16));
    v = fmaxf(v, __shfl_xor(v, 32));
    if (lane < 16) smax[wr][wc*64 + fb*16 + lane] = v;
  }
  __syncthreads();
  if (tid < 128){
    const float v = fmaxf(smax[0][tid], smax[1][tid]);
    const int hgl = hc0 + tid;
    const float prev = feats[(size_t)i*1536 + it*512 + hgl];
    feats[(size_t)i*1536 + 512 + it*512 + hgl] = (*flag) ? v : prev;
  }
}

// ---------------------------------------------------------------------------
extern "C" void kernel_launch(void* const* d_in, const int* in_sizes, int n_in,
                              void* d_out, int out_size, void* d_ws, size_t ws_size,
                              hipStream_t stream)
{
  const float* pf   = (const float*)d_in[0];
  const float* Wp   = (const float*)d_in[1];
  const float* bp   = (const float*)d_in[2];
  const float* We   = (const float*)d_in[3];
  const float* be   = (const float*)d_in[4];
  const float* Wsem = (const float*)d_in[5];
  const float* bsem = (const float*)d_in[6];
  const float* Wel  = (const float*)d_in[7];
  const float* bel  = (const float*)d_in[8];
  const float* Wee  = (const float*)d_in[9];
  const float* bee  = (const float*)d_in[10];
  const float* Wop  = (const float*)d_in[11];
  const float* bop  = (const float*)d_in[12];
  const float* Wc   = (const float*)d_in[13];
  const float* bc   = (const float*)d_in[14];
  const float* Wc2  = (const float*)d_in[15];
  const float* bc2  = (const float*)d_in[16];

  float* out      = (float*)d_out;
  float* out_cf   = out;             // [128,512]
  float* out_sem  = out + 65536;     // [128,50]
  float* out_ex   = out + 71936;     // [128]
  float* out_eel  = out + 72064;     // [128,128,4]

  char* ws = (char*)d_ws;
  u16*   elb   = (u16*)ws;                                // 16 MB bf16 el
  float* feats = (float*)(ws + 16777216);                 // [128][1536]
  float* P     = feats + 196608;                          // [128][512]
  float* Q     = P + 65536;
  float* wsA   = Q + 65536;
  float* wsB   = wsA + 65536;
  float* wsH   = wsB + 65536;
  float* exw   = wsH + 65536;                             // [128]
  int*   flag  = (int*)(exw + 128);
  u16*   wfb   = (u16*)(flag + 4);                        // [2][512][512] bf16

  wconv_kernel<<<256, 256, 0, stream>>>(Wop, wfb);
  cf_kernel<<<16384, 256, 0, stream>>>(Wp, pf, bp, feats, flag);
  // exists -> d_out + ws copy
  gemm_dot<false><<<dim3(1, 16), 256, 0, stream>>>(feats, 1536, We, 512, be,
                                                   out_ex, 1, exw, 1, 512);
  // P (with bel), Q
  gemm_dot<false><<<dim3(128, 16), 256, 0, stream>>>(feats, 1536, Wel, 1024, bel,
                                                     P, 512, nullptr, 512, 512);
  gemm_dot<false><<<dim3(128, 16), 256, 0, stream>>>(feats, 1536, Wel + 512, 1024, nullptr,
                                                     Q, 512, nullptr, 512, 512);
  el_kernel<<<4096, 256, 0, stream>>>(P, Q, Wee, bee, exw, elb, out_eel, flag);

  for (int it = 0; it < 2; it++){
    const float* Wit = Wop + (size_t)it * 788480;
    gemm_dot<false><<<dim3(128, 16), 256, 0, stream>>>(feats + it*512, 1536, Wit, 1540,
                                                       bop + it*512, wsA, 512, nullptr, 512, 512);
    gemm_dot<false><<<dim3(128, 16), 256, 0, stream>>>(feats + it*512, 1536, Wit + 512, 1540,
                                                       nullptr, wsB, 512, nullptr, 512, 512);
    iter_kernel<<<dim3(4, 128), 256, 0, stream>>>(elb, wfb + it*262144, wsA, wsB,
                                                  out_eel, exw, Wit, flag, feats, it);
  }
  // head
  gemm_dot<true><<<dim3(128, 16), 256, 0, stream>>>(feats, 1536, Wc, 1536, bc,
                                                    wsH, 512, nullptr, 512, 1536);
  gemm_dot<false><<<dim3(13, 16), 256, 0, stream>>>(wsH, 512, Wsem, 512, bsem,
                                                    out_sem, 50, nullptr, 50, 512);
  gemm_dot<true><<<dim3(128, 16), 256, 0, stream>>>(wsH, 512, Wc2, 512, bc2,
                                                    out_cf, 512, nullptr, 512, 512);
}